// Round 1
// baseline (362.302 us; speedup 1.0000x reference)
//
#include <hip/hip_runtime.h>

namespace {
constexpr int kV = 256, kO = 128, kE = 1024, kD = 128;
constexpr int kN = kV * kO;    // 32768 nodes
constexpr int kVE = kV * kE;   // 262144 edges
constexpr float kEps = 1e-5f;
}

// ---- K0: detect whether edges buffer is int64 (hi words all zero) or int32 ----
__global__ void k_detect(const unsigned int* __restrict__ ew, int* __restrict__ flag) {
  __shared__ int any;
  if (threadIdx.x == 0) any = 0;
  __syncthreads();
  int local = 0;
  for (int i = threadIdx.x; i < 8192; i += blockDim.x)
    if (ew[2 * i + 1] != 0u) local = 1;
  if (local) atomicOr(&any, 1);
  __syncthreads();
  if (threadIdx.x == 0) *flag = (any == 0) ? 1 : 0;  // 1 => int64 layout
}

// ---- K1: per-graph CSR (edges grouped by source node, order-preserving) + counts ----
__global__ __launch_bounds__(256) void k_csr(
    const unsigned int* __restrict__ ew, const int* __restrict__ flag,
    int* __restrict__ cnt_s, int* __restrict__ cnt_o,
    int* __restrict__ csr_off, unsigned char* __restrict__ csr_col) {
  __shared__ unsigned char s_l[kE], o_l[kE];
  __shared__ int c_s[kO], c_o[kO], offs[kO + 1];
  int v = blockIdx.x, t = threadIdx.x;
  bool is64 = (*flag != 0);
  for (int i = t; i < kO; i += 256) { c_s[i] = 0; c_o[i] = 0; }
  __syncthreads();
  for (int e = t; e < kE; e += 256) {
    long long base = (long long)(v * kE + e) * 3;
    unsigned int s, o;
    if (is64) { s = ew[2 * (base + 0)]; o = ew[2 * (base + 2)]; }
    else      { s = ew[base + 0];       o = ew[base + 2]; }
    s &= 127u; o &= 127u;
    s_l[e] = (unsigned char)s; o_l[e] = (unsigned char)o;
    atomicAdd(&c_s[s], 1); atomicAdd(&c_o[o], 1);
  }
  __syncthreads();
  if (t == 0) {
    int acc = 0;
    for (int i = 0; i < kO; ++i) { offs[i] = acc; acc += c_s[i]; }
    offs[kO] = acc;
  }
  __syncthreads();
  if (t < kO) {
    cnt_s[v * kO + t] = c_s[t];
    cnt_o[v * kO + t] = c_o[t];
    csr_off[v * (kO + 1) + t] = offs[t];
    if (t == 0) csr_off[v * (kO + 1) + kO] = offs[kO];
    int pos = offs[t];
    for (int i = 0; i < kE; ++i)              // deterministic, order-preserving fill
      if (s_l[i] == (unsigned char)t) csr_col[v * kE + (pos++)] = o_l[i];
  }
}

// ---- K2: count-weighted per-column sums / sumsq of x (BN1 stats partials) ----
__global__ __launch_bounds__(256) void k_stats1(
    const float* __restrict__ x, const int* __restrict__ cnt_s,
    const int* __restrict__ cnt_o, float* __restrict__ p1) {
  __shared__ float red[8][128];
  int b = blockIdx.x, t = threadIdx.x;
  int dq = (t & 31) * 4, rg = t >> 5;
  float acc[4][4];
#pragma unroll
  for (int a = 0; a < 4; ++a)
#pragma unroll
    for (int j = 0; j < 4; ++j) acc[a][j] = 0.f;
  for (int k = 0; k < 16; ++k) {
    int n = b * 128 + rg + k * 8;
    float4 xv = *(const float4*)(x + (size_t)n * kD + dq);
    float wsv = (float)cnt_s[n], wov = (float)cnt_o[n];
    float xs[4] = {xv.x, xv.y, xv.z, xv.w};
#pragma unroll
    for (int j = 0; j < 4; ++j) {
      acc[0][j] += wsv * xs[j];
      acc[1][j] += wsv * xs[j] * xs[j];
      acc[2][j] += wov * xs[j];
      acc[3][j] += wov * xs[j] * xs[j];
    }
  }
  for (int st = 0; st < 4; ++st) {
    __syncthreads();
#pragma unroll
    for (int j = 0; j < 4; ++j) red[rg][dq + j] = acc[st][j];
    __syncthreads();
    if (t < 128) {
      float s = 0.f;
#pragma unroll
      for (int g = 0; g < 8; ++g) s += red[g][t];
      p1[((size_t)b * 4 + st) * 128 + t] = s;
    }
  }
}

// ---- K3: finalize BN1 -> affine coeffs a,beta for src half and dst half ----
__global__ void k_fin1(const float* __restrict__ p1, const float* __restrict__ g1,
                       const float* __restrict__ b1, float* __restrict__ coef) {
  int c = threadIdx.x;  // 0..255 = column of the 2D-wide BN
  if (c >= 256) return;
  int half = c >> 7, d = c & 127;
  double S = 0.0, Q = 0.0;
  for (int b = 0; b < 256; ++b) {
    S += p1[((size_t)b * 4 + half * 2 + 0) * 128 + d];
    Q += p1[((size_t)b * 4 + half * 2 + 1) * 128 + d];
  }
  double m = S / (double)kVE;
  double var = Q / (double)kVE - m * m;
  float a = g1[c] / sqrtf((float)var + kEps);
  float beta = b1[c] - (float)m * a;
  coef[half * 256 + d] = a;
  coef[half * 256 + 128 + d] = beta;
}

// ---- GEMM: Y[n][j] = sum_d relu(a[d]*X[n][d]+beta[d]) * W[j][colOff+d] (+bias)(+resid) ----
__global__ __launch_bounds__(256, 1) void k_gemm(
    const float* __restrict__ X, const float* __restrict__ Wg, int wStride, int wColOff,
    const float* __restrict__ coefA, const float* __restrict__ coefB,
    float* __restrict__ Y, const float* __restrict__ bias, const float* __restrict__ resid) {
  __shared__ __align__(16) float hl[128 * 128];
  __shared__ __align__(16) float wl[128 * 128];
  int t = threadIdx.x, rb = blockIdx.x;
  int dq = (t & 31) * 4, rg = t >> 5;
  // stage W tile (swizzled: XOR row-bits 3..5 into word bits 2..4)
  for (int k = 0; k < 16; ++k) {
    int j = rg + k * 8;
    float4 wv = *(const float4*)(Wg + (size_t)j * wStride + wColOff + dq);
    *(float4*)(wl + j * 128 + (dq ^ (((j >> 3) & 7) << 2))) = wv;
  }
  // stage h tile = relu(a*x+beta), same swizzle
  float4 av = *(const float4*)(coefA + dq);
  float4 bv = *(const float4*)(coefB + dq);
  for (int k = 0; k < 16; ++k) {
    int r = rg + k * 8;
    float4 xv = *(const float4*)(X + ((size_t)rb * 128 + r) * kD + dq);
    float4 hv;
    hv.x = fmaxf(av.x * xv.x + bv.x, 0.f);
    hv.y = fmaxf(av.y * xv.y + bv.y, 0.f);
    hv.z = fmaxf(av.z * xv.z + bv.z, 0.f);
    hv.w = fmaxf(av.w * xv.w + bv.w, 0.f);
    *(float4*)(hl + r * 128 + (dq ^ (((r >> 3) & 7) << 2))) = hv;
  }
  __syncthreads();
  int tc = t & 15, tr = t >> 4;
  int r0 = tr * 8, j0 = tc * 8;
  int hswz = (tr & 7) << 2, wswz = (tc & 7) << 2;
  float acc[8][8];
#pragma unroll
  for (int i = 0; i < 8; ++i)
#pragma unroll
    for (int k = 0; k < 8; ++k) acc[i][k] = 0.f;
  for (int d0 = 0; d0 < 128; d0 += 4) {
    int hd = d0 ^ hswz, wd = d0 ^ wswz;
    float4 hv[8], wv[8];
#pragma unroll
    for (int i = 0; i < 8; ++i) hv[i] = *(const float4*)(hl + (r0 + i) * 128 + hd);
#pragma unroll
    for (int k = 0; k < 8; ++k) wv[k] = *(const float4*)(wl + (j0 + k) * 128 + wd);
#pragma unroll
    for (int i = 0; i < 8; ++i)
#pragma unroll
      for (int k = 0; k < 8; ++k)
        acc[i][k] += hv[i].x * wv[k].x + hv[i].y * wv[k].y +
                     hv[i].z * wv[k].z + hv[i].w * wv[k].w;
  }
  float bsum[8];
#pragma unroll
  for (int k = 0; k < 8; ++k) bsum[k] = bias ? bias[j0 + k] : 0.f;
#pragma unroll
  for (int i = 0; i < 8; ++i) {
    size_t n = (size_t)rb * 128 + r0 + i;
    float out[8];
#pragma unroll
    for (int k = 0; k < 8; ++k) out[k] = acc[i][k] + bsum[k];
    if (resid) {
      float4 r1 = *(const float4*)(resid + n * kD + j0);
      float4 r2 = *(const float4*)(resid + n * kD + j0 + 4);
      out[0] += r1.x; out[1] += r1.y; out[2] += r1.z; out[3] += r1.w;
      out[4] += r2.x; out[5] += r2.y; out[6] += r2.z; out[7] += r2.w;
    }
    *(float4*)(Y + n * kD + j0)     = make_float4(out[0], out[1], out[2], out[3]);
    *(float4*)(Y + n * kD + j0 + 4) = make_float4(out[4], out[5], out[6], out[7]);
  }
}

// ---- K5: per-graph pooled = ys + lb1 + mean of yo over out-edges; fused BN2 partials ----
__global__ __launch_bounds__(256) void k_pool(
    const float* __restrict__ ys, const float* __restrict__ yo,
    const int* __restrict__ csr_off, const unsigned char* __restrict__ csr_col,
    const float* __restrict__ lb1, float* __restrict__ pooled, float* __restrict__ p2) {
  __shared__ __align__(16) float yol[kO * kD];
  __shared__ unsigned char coll[kE];
  __shared__ int offl[kO + 1];
  __shared__ float red[4][128];
  int v = blockIdx.x, t = threadIdx.x;
  int dq = (t & 31) * 4, rg = t >> 5;
  for (int k = 0; k < 16; ++k) {
    int o = rg + k * 8;
    *(float4*)(yol + o * kD + dq) =
        *(const float4*)(yo + ((size_t)(v * kO + o)) * kD + dq);
  }
  for (int i = t; i < kE; i += 256) coll[i] = csr_col[v * kE + i];
  if (t <= kO) offl[t] = csr_off[v * (kO + 1) + t];
  __syncthreads();
  int w = t >> 6, l = t & 63;
  int d0 = l * 2;
  float sm0 = 0, sm1 = 0, sq0 = 0, sq1 = 0;
  for (int s = w; s < kO; s += 4) {
    int c0 = offl[s], c1 = offl[s + 1];
    float a0 = 0.f, a1 = 0.f;
    int e = c0;
    for (; e + 4 <= c1; e += 4) {
      int o0 = coll[e], o1 = coll[e + 1], o2 = coll[e + 2], o3 = coll[e + 3];
      float2 y0 = *(const float2*)(yol + o0 * kD + d0);
      float2 y1 = *(const float2*)(yol + o1 * kD + d0);
      float2 y2 = *(const float2*)(yol + o2 * kD + d0);
      float2 y3 = *(const float2*)(yol + o3 * kD + d0);
      a0 += y0.x + y1.x + y2.x + y3.x;
      a1 += y0.y + y1.y + y2.y + y3.y;
    }
    for (; e < c1; ++e) {
      int o = coll[e];
      float2 yv = *(const float2*)(yol + o * kD + d0);
      a0 += yv.x; a1 += yv.y;
    }
    int cnt = c1 - c0;
    size_t n = (size_t)v * kO + s;
    float pv0 = 0.f, pv1 = 0.f;
    if (cnt > 0) {
      float inv = 1.f / (float)cnt;
      float2 yv = *(const float2*)(ys + n * kD + d0);
      float2 lv = *(const float2*)(lb1 + d0);
      pv0 = yv.x + lv.x + a0 * inv;
      pv1 = yv.y + lv.y + a1 * inv;
    }
    *(float2*)(pooled + n * kD + d0) = make_float2(pv0, pv1);
    sm0 += pv0; sm1 += pv1; sq0 += pv0 * pv0; sq1 += pv1 * pv1;
  }
  red[w][d0] = sm0; red[w][d0 + 1] = sm1;
  __syncthreads();
  if (t < 128) {
    float s = red[0][t] + red[1][t] + red[2][t] + red[3][t];
    p2[((size_t)v * 2 + 0) * 128 + t] = s;
  }
  __syncthreads();
  red[w][d0] = sq0; red[w][d0 + 1] = sq1;
  __syncthreads();
  if (t < 128) {
    float s = red[0][t] + red[1][t] + red[2][t] + red[3][t];
    p2[((size_t)v * 2 + 1) * 128 + t] = s;
  }
}

// ---- K6: finalize BN2 coeffs ----
__global__ void k_fin2(const float* __restrict__ p2, const float* __restrict__ g2,
                       const float* __restrict__ b2, float* __restrict__ coef2) {
  int d = threadIdx.x;
  if (d >= 128) return;
  double S = 0.0, Q = 0.0;
  for (int v = 0; v < kV; ++v) {
    S += p2[((size_t)v * 2 + 0) * 128 + d];
    Q += p2[((size_t)v * 2 + 1) * 128 + d];
  }
  double m = S / (double)kN, var = Q / (double)kN - m * m;
  float a = g2[d] / sqrtf((float)var + kEps);
  float beta = b2[d] - (float)m * a;
  coef2[d] = a; coef2[128 + d] = beta;
}

extern "C" void kernel_launch(void* const* d_in, const int* in_sizes, int n_in,
                              void* d_out, int out_size, void* d_ws, size_t ws_size,
                              hipStream_t stream) {
  (void)in_sizes; (void)n_in; (void)out_size; (void)ws_size;
  const float* obj = (const float*)d_in[0];
  const unsigned int* ew = (const unsigned int*)d_in[1];
  const float* prm[2][8];
  for (int u = 0; u < 2; ++u)
    for (int p = 0; p < 8; ++p) prm[u][p] = (const float*)d_in[2 + u * 8 + p];
  // prm[u]: 0=g1 1=b1 2=W1 3=lb1 4=g2 5=b2 6=W2 7=lb2

  char* ws = (char*)d_ws;
  size_t off = 0;
  auto carve = [&](size_t bytes) -> char* {
    char* p = ws + off;
    off = (off + bytes + 255) & ~(size_t)255;
    return p;
  };
  int* flag = (int*)carve(4);
  int* cnt_s = (int*)carve((size_t)kN * 4);
  int* cnt_o = (int*)carve((size_t)kN * 4);
  int* csr_off = (int*)carve((size_t)kV * (kO + 1) * 4);
  unsigned char* csr_col = (unsigned char*)carve(kVE);
  float* p1 = (float*)carve((size_t)256 * 4 * 128 * 4);
  float* p2 = (float*)carve((size_t)kV * 2 * 128 * 4);
  float* coef1 = (float*)carve(512 * 4);
  float* coef2 = (float*)carve(256 * 4);
  float* ys = (float*)carve((size_t)kN * kD * 4);
  float* yo = (float*)carve((size_t)kN * kD * 4);
  float* pooled = (float*)carve((size_t)kN * kD * 4);
  float* x2 = (float*)carve((size_t)kN * kD * 4);

  k_detect<<<1, 256, 0, stream>>>(ew, flag);
  k_csr<<<kV, 256, 0, stream>>>(ew, flag, cnt_s, cnt_o, csr_off, csr_col);

  float* outp = (float*)d_out;
  for (int u = 0; u < 2; ++u) {
    const float* x = (u == 0) ? obj : x2;
    k_stats1<<<256, 256, 0, stream>>>(x, cnt_s, cnt_o, p1);
    k_fin1<<<1, 256, 0, stream>>>(p1, prm[u][0], prm[u][1], coef1);
    k_gemm<<<kN / 128, 256, 0, stream>>>(x, prm[u][2], 2 * kD, 0,
                                         coef1, coef1 + 128, ys, nullptr, nullptr);
    k_gemm<<<kN / 128, 256, 0, stream>>>(x, prm[u][2], 2 * kD, kD,
                                         coef1 + 256, coef1 + 384, yo, nullptr, nullptr);
    k_pool<<<kV, 256, 0, stream>>>(ys, yo, csr_off, csr_col, prm[u][3], pooled, p2);
    k_fin2<<<1, 128, 0, stream>>>(p2, prm[u][4], prm[u][5], coef2);
    k_gemm<<<kN / 128, 256, 0, stream>>>(pooled, prm[u][6], kD, 0,
                                         coef2, coef2 + 128,
                                         (u == 0) ? x2 : outp, prm[u][7],
                                         (u == 0) ? nullptr : obj);
  }
}

// Round 2
// 296.854 us; speedup vs baseline: 1.2205x; 1.2205x over previous
//
#include <hip/hip_runtime.h>

namespace {
constexpr int kV = 256, kO = 128, kE = 1024, kD = 128;
constexpr int kN = kV * kO;    // 32768 nodes
constexpr int kVE = kV * kE;   // 262144 edges
constexpr float kEps = 1e-5f;
}

// ---- K0: detect whether edges buffer is int64 (hi words all zero) or int32 ----
__global__ void k_detect(const unsigned int* __restrict__ ew, int* __restrict__ flag) {
  __shared__ int any;
  if (threadIdx.x == 0) any = 0;
  __syncthreads();
  int local = 0;
  for (int i = threadIdx.x; i < 8192; i += blockDim.x)
    if (ew[2 * i + 1] != 0u) local = 1;
  if (local) atomicOr(&any, 1);
  __syncthreads();
  if (threadIdx.x == 0) *flag = (any == 0) ? 1 : 0;  // 1 => int64 layout
}

// ---- K1: per-graph count matrix A[s][o] + row/col sums (src/dst degree) ----
__global__ __launch_bounds__(256) void k_adj(
    const unsigned int* __restrict__ ew, const int* __restrict__ flag,
    int* __restrict__ cnt_s, int* __restrict__ cnt_o,
    unsigned short* __restrict__ A) {
  __shared__ int cnt[kO * kO];  // 64 KiB
  int v = blockIdx.x, t = threadIdx.x;
  for (int i = t; i < kO * kO; i += 256) cnt[i] = 0;
  __syncthreads();
  bool is64 = (*flag != 0);
  for (int e = t; e < kE; e += 256) {
    long long base = (long long)(v * kE + e) * 3;
    unsigned int s, o;
    if (is64) { s = ew[2 * (base + 0)]; o = ew[2 * (base + 2)]; }
    else      { s = ew[base + 0];       o = ew[base + 2]; }
    s &= 127u; o &= 127u;
    atomicAdd(&cnt[s * kO + o], 1);
  }
  __syncthreads();
  // pack to u16 global
  unsigned int* A32 = (unsigned int*)(A + (size_t)v * kO * kO);
  for (int i = t; i < kO * kO / 2; i += 256) {
    unsigned int lo = (unsigned int)cnt[2 * i], hi = (unsigned int)cnt[2 * i + 1];
    A32[i] = lo | (hi << 16);
  }
  // degree sums (staggered start to avoid stride-128 bank conflicts)
  if (t < kO) {
    int s = 0;
    for (int c = 0; c < kO; ++c) s += cnt[t * kO + ((c + t) & 127)];
    cnt_s[v * kO + t] = s;
  } else {
    int tc = t - kO;
    int s = 0;
    for (int r = 0; r < kO; ++r) s += cnt[((r + tc) & 127) * kO + tc];
    cnt_o[v * kO + tc] = s;
  }
}

// ---- K2: count-weighted per-column sums / sumsq of x (BN1 stats partials) ----
__global__ __launch_bounds__(256) void k_stats1(
    const float* __restrict__ x, const int* __restrict__ cnt_s,
    const int* __restrict__ cnt_o, float* __restrict__ p1) {
  __shared__ float red[8][128];
  int b = blockIdx.x, t = threadIdx.x;
  int dq = (t & 31) * 4, rg = t >> 5;
  float acc[4][4];
#pragma unroll
  for (int a = 0; a < 4; ++a)
#pragma unroll
    for (int j = 0; j < 4; ++j) acc[a][j] = 0.f;
  for (int k = 0; k < 16; ++k) {
    int n = b * 128 + rg + k * 8;
    float4 xv = *(const float4*)(x + (size_t)n * kD + dq);
    float wsv = (float)cnt_s[n], wov = (float)cnt_o[n];
    float xs[4] = {xv.x, xv.y, xv.z, xv.w};
#pragma unroll
    for (int j = 0; j < 4; ++j) {
      acc[0][j] += wsv * xs[j];
      acc[1][j] += wsv * xs[j] * xs[j];
      acc[2][j] += wov * xs[j];
      acc[3][j] += wov * xs[j] * xs[j];
    }
  }
  for (int st = 0; st < 4; ++st) {
    __syncthreads();
#pragma unroll
    for (int j = 0; j < 4; ++j) red[rg][dq + j] = acc[st][j];
    __syncthreads();
    if (t < 128) {
      float s = 0.f;
#pragma unroll
      for (int g = 0; g < 8; ++g) s += red[g][t];
      p1[((size_t)b * 4 + st) * 128 + t] = s;
    }
  }
}

// ---- K3: finalize BN1 -> affine coeffs a,beta for src half and dst half ----
__global__ void k_fin1(const float* __restrict__ p1, const float* __restrict__ g1,
                       const float* __restrict__ b1, float* __restrict__ coef) {
  int c = threadIdx.x;  // 0..255 = column of the 2D-wide BN
  if (c >= 256) return;
  int half = c >> 7, d = c & 127;
  double S = 0.0, Q = 0.0;
  for (int b = 0; b < 256; ++b) {
    S += p1[((size_t)b * 4 + half * 2 + 0) * 128 + d];
    Q += p1[((size_t)b * 4 + half * 2 + 1) * 128 + d];
  }
  double m = S / (double)kVE;
  double var = Q / (double)kVE - m * m;
  float a = g1[c] / sqrtf((float)var + kEps);
  float beta = b1[c] - (float)m * a;
  coef[half * 256 + d] = a;
  coef[half * 256 + 128 + d] = beta;
}

// ---- GEMM: Y[n][j] = sum_d relu(a[d]*X[n][d]+beta[d]) * W[j][colOff+d] (+bias)(+resid) ----
__global__ __launch_bounds__(256, 1) void k_gemm(
    const float* __restrict__ X, const float* __restrict__ Wg, int wStride, int wColOff,
    const float* __restrict__ coefA, const float* __restrict__ coefB,
    float* __restrict__ Y, const float* __restrict__ bias, const float* __restrict__ resid) {
  __shared__ __align__(16) float hl[128 * 128];
  __shared__ __align__(16) float wl[128 * 128];
  int t = threadIdx.x, rb = blockIdx.x;
  int dq = (t & 31) * 4, rg = t >> 5;
  for (int k = 0; k < 16; ++k) {
    int j = rg + k * 8;
    float4 wv = *(const float4*)(Wg + (size_t)j * wStride + wColOff + dq);
    *(float4*)(wl + j * 128 + (dq ^ (((j >> 3) & 7) << 2))) = wv;
  }
  float4 av = *(const float4*)(coefA + dq);
  float4 bv = *(const float4*)(coefB + dq);
  for (int k = 0; k < 16; ++k) {
    int r = rg + k * 8;
    float4 xv = *(const float4*)(X + ((size_t)rb * 128 + r) * kD + dq);
    float4 hv;
    hv.x = fmaxf(av.x * xv.x + bv.x, 0.f);
    hv.y = fmaxf(av.y * xv.y + bv.y, 0.f);
    hv.z = fmaxf(av.z * xv.z + bv.z, 0.f);
    hv.w = fmaxf(av.w * xv.w + bv.w, 0.f);
    *(float4*)(hl + r * 128 + (dq ^ (((r >> 3) & 7) << 2))) = hv;
  }
  __syncthreads();
  int tc = t & 15, tr = t >> 4;
  int r0 = tr * 8, j0 = tc * 8;
  int hswz = (tr & 7) << 2, wswz = (tc & 7) << 2;
  float acc[8][8];
#pragma unroll
  for (int i = 0; i < 8; ++i)
#pragma unroll
    for (int k = 0; k < 8; ++k) acc[i][k] = 0.f;
  for (int d0 = 0; d0 < 128; d0 += 4) {
    int hd = d0 ^ hswz, wd = d0 ^ wswz;
    float4 hv[8], wv[8];
#pragma unroll
    for (int i = 0; i < 8; ++i) hv[i] = *(const float4*)(hl + (r0 + i) * 128 + hd);
#pragma unroll
    for (int k = 0; k < 8; ++k) wv[k] = *(const float4*)(wl + (j0 + k) * 128 + wd);
#pragma unroll
    for (int i = 0; i < 8; ++i)
#pragma unroll
      for (int k = 0; k < 8; ++k)
        acc[i][k] += hv[i].x * wv[k].x + hv[i].y * wv[k].y +
                     hv[i].z * wv[k].z + hv[i].w * wv[k].w;
  }
  float bsum[8];
#pragma unroll
  for (int k = 0; k < 8; ++k) bsum[k] = bias ? bias[j0 + k] : 0.f;
#pragma unroll
  for (int i = 0; i < 8; ++i) {
    size_t n = (size_t)rb * 128 + r0 + i;
    float out[8];
#pragma unroll
    for (int k = 0; k < 8; ++k) out[k] = acc[i][k] + bsum[k];
    if (resid) {
      float4 r1 = *(const float4*)(resid + n * kD + j0);
      float4 r2 = *(const float4*)(resid + n * kD + j0 + 4);
      out[0] += r1.x; out[1] += r1.y; out[2] += r1.z; out[3] += r1.w;
      out[4] += r2.x; out[5] += r2.y; out[6] += r2.z; out[7] += r2.w;
    }
    *(float4*)(Y + n * kD + j0)     = make_float4(out[0], out[1], out[2], out[3]);
    *(float4*)(Y + n * kD + j0 + 4) = make_float4(out[4], out[5], out[6], out[7]);
  }
}

// ---- K5: per-graph pooled = ys + lb1 + (A @ yo) / cnt ; fused BN2 partials ----
__global__ __launch_bounds__(256, 1) void k_poolg(
    const float* __restrict__ ys, const float* __restrict__ yo,
    const unsigned short* __restrict__ A, const float* __restrict__ lb1,
    float* __restrict__ pooled, float* __restrict__ p2) {
  __shared__ __align__(16) float Af[kO * kO];   // [s][k] swizzled
  __shared__ __align__(16) float yol[kO * kD];  // [k][d] linear
  int v = blockIdx.x, t = threadIdx.x;
  int dq = (t & 31) * 4, rg = t >> 5;
  // stage A (u16 -> float, swizzle k-index with row bits 3..5)
  const unsigned int* A32 = (const unsigned int*)(A + (size_t)v * kO * kO);
  for (int k = 0; k < 32; ++k) {
    int idx = t + k * 256;        // u32 index over 8192
    unsigned int a2 = A32[idx];
    int base = idx * 2;
    int row = base >> 7, col = base & 127;
    int sw = col ^ (((row >> 3) & 7) << 2);
    float2 f = make_float2((float)(a2 & 0xFFFFu), (float)(a2 >> 16));
    *(float2*)(Af + row * kO + sw) = f;
  }
  // stage yo tile (linear)
  for (int k = 0; k < 16; ++k) {
    int r = rg + k * 8;
    *(float4*)(yol + r * kD + dq) =
        *(const float4*)(yo + ((size_t)(v * kO + r)) * kD + dq);
  }
  __syncthreads();
  int tc = t & 15, tr = t >> 4;
  int r0 = tr * 8, j0 = tc * 8;
  int asw = (tr & 7) << 2;
  float acc[8][8], rs[8];
#pragma unroll
  for (int i = 0; i < 8; ++i) {
    rs[i] = 0.f;
#pragma unroll
    for (int k = 0; k < 8; ++k) acc[i][k] = 0.f;
  }
  for (int k0 = 0; k0 < 128; k0 += 4) {
    int ad = k0 ^ asw;
    float4 av[8];
#pragma unroll
    for (int i = 0; i < 8; ++i) av[i] = *(const float4*)(Af + (r0 + i) * kO + ad);
    float4 b0[4], b1[4];
#pragma unroll
    for (int kk = 0; kk < 4; ++kk) {
      b0[kk] = *(const float4*)(yol + (k0 + kk) * kD + j0);
      b1[kk] = *(const float4*)(yol + (k0 + kk) * kD + j0 + 4);
    }
#pragma unroll
    for (int i = 0; i < 8; ++i) {
      rs[i] += av[i].x + av[i].y + av[i].z + av[i].w;
      acc[i][0] += av[i].x * b0[0].x + av[i].y * b0[1].x + av[i].z * b0[2].x + av[i].w * b0[3].x;
      acc[i][1] += av[i].x * b0[0].y + av[i].y * b0[1].y + av[i].z * b0[2].y + av[i].w * b0[3].y;
      acc[i][2] += av[i].x * b0[0].z + av[i].y * b0[1].z + av[i].z * b0[2].z + av[i].w * b0[3].z;
      acc[i][3] += av[i].x * b0[0].w + av[i].y * b0[1].w + av[i].z * b0[2].w + av[i].w * b0[3].w;
      acc[i][4] += av[i].x * b1[0].x + av[i].y * b1[1].x + av[i].z * b1[2].x + av[i].w * b1[3].x;
      acc[i][5] += av[i].x * b1[0].y + av[i].y * b1[1].y + av[i].z * b1[2].y + av[i].w * b1[3].y;
      acc[i][6] += av[i].x * b1[0].z + av[i].y * b1[1].z + av[i].z * b1[2].z + av[i].w * b1[3].z;
      acc[i][7] += av[i].x * b1[0].w + av[i].y * b1[1].w + av[i].z * b1[2].w + av[i].w * b1[3].w;
    }
  }
  // epilogue: pooled + BN2 partials
  __syncthreads();  // done reading Af/yol; reuse Af as reduction scratch
  float4 lv1 = *(const float4*)(lb1 + j0);
  float4 lv2 = *(const float4*)(lb1 + j0 + 4);
  float lb[8] = {lv1.x, lv1.y, lv1.z, lv1.w, lv2.x, lv2.y, lv2.z, lv2.w};
  float sm[8], sq[8];
#pragma unroll
  for (int k = 0; k < 8; ++k) { sm[k] = 0.f; sq[k] = 0.f; }
#pragma unroll
  for (int i = 0; i < 8; ++i) {
    size_t n = (size_t)v * kO + r0 + i;
    float pv[8];
    if (rs[i] > 0.f) {
      float inv = 1.f / rs[i];
      float4 y1 = *(const float4*)(ys + n * kD + j0);
      float4 y2 = *(const float4*)(ys + n * kD + j0 + 4);
      float yv[8] = {y1.x, y1.y, y1.z, y1.w, y2.x, y2.y, y2.z, y2.w};
#pragma unroll
      for (int k = 0; k < 8; ++k) pv[k] = yv[k] + lb[k] + acc[i][k] * inv;
    } else {
#pragma unroll
      for (int k = 0; k < 8; ++k) pv[k] = 0.f;
    }
    *(float4*)(pooled + n * kD + j0)     = make_float4(pv[0], pv[1], pv[2], pv[3]);
    *(float4*)(pooled + n * kD + j0 + 4) = make_float4(pv[4], pv[5], pv[6], pv[7]);
#pragma unroll
    for (int k = 0; k < 8; ++k) { sm[k] += pv[k]; sq[k] += pv[k] * pv[k]; }
  }
  float* red = Af;  // [16][128]
  *(float4*)(red + tr * 128 + j0)     = make_float4(sm[0], sm[1], sm[2], sm[3]);
  *(float4*)(red + tr * 128 + j0 + 4) = make_float4(sm[4], sm[5], sm[6], sm[7]);
  __syncthreads();
  if (t < 128) {
    float s = 0.f;
#pragma unroll
    for (int g = 0; g < 16; ++g) s += red[g * 128 + t];
    p2[((size_t)v * 2 + 0) * 128 + t] = s;
  }
  __syncthreads();
  *(float4*)(red + tr * 128 + j0)     = make_float4(sq[0], sq[1], sq[2], sq[3]);
  *(float4*)(red + tr * 128 + j0 + 4) = make_float4(sq[4], sq[5], sq[6], sq[7]);
  __syncthreads();
  if (t < 128) {
    float s = 0.f;
#pragma unroll
    for (int g = 0; g < 16; ++g) s += red[g * 128 + t];
    p2[((size_t)v * 2 + 1) * 128 + t] = s;
  }
}

// ---- K6: finalize BN2 coeffs ----
__global__ void k_fin2(const float* __restrict__ p2, const float* __restrict__ g2,
                       const float* __restrict__ b2, float* __restrict__ coef2) {
  int d = threadIdx.x;
  if (d >= 128) return;
  double S = 0.0, Q = 0.0;
  for (int v = 0; v < kV; ++v) {
    S += p2[((size_t)v * 2 + 0) * 128 + d];
    Q += p2[((size_t)v * 2 + 1) * 128 + d];
  }
  double m = S / (double)kN, var = Q / (double)kN - m * m;
  float a = g2[d] / sqrtf((float)var + kEps);
  float beta = b2[d] - (float)m * a;
  coef2[d] = a; coef2[128 + d] = beta;
}

extern "C" void kernel_launch(void* const* d_in, const int* in_sizes, int n_in,
                              void* d_out, int out_size, void* d_ws, size_t ws_size,
                              hipStream_t stream) {
  (void)in_sizes; (void)n_in; (void)out_size; (void)ws_size;
  const float* obj = (const float*)d_in[0];
  const unsigned int* ew = (const unsigned int*)d_in[1];
  const float* prm[2][8];
  for (int u = 0; u < 2; ++u)
    for (int p = 0; p < 8; ++p) prm[u][p] = (const float*)d_in[2 + u * 8 + p];
  // prm[u]: 0=g1 1=b1 2=W1 3=lb1 4=g2 5=b2 6=W2 7=lb2

  char* ws = (char*)d_ws;
  size_t off = 0;
  auto carve = [&](size_t bytes) -> char* {
    char* p = ws + off;
    off = (off + bytes + 255) & ~(size_t)255;
    return p;
  };
  int* flag = (int*)carve(4);
  int* cnt_s = (int*)carve((size_t)kN * 4);
  int* cnt_o = (int*)carve((size_t)kN * 4);
  unsigned short* Amat = (unsigned short*)carve((size_t)kV * kO * kO * 2);
  float* p1 = (float*)carve((size_t)256 * 4 * 128 * 4);
  float* p2 = (float*)carve((size_t)kV * 2 * 128 * 4);
  float* coef1 = (float*)carve(512 * 4);
  float* coef2 = (float*)carve(256 * 4);
  float* ys = (float*)carve((size_t)kN * kD * 4);
  float* yo = (float*)carve((size_t)kN * kD * 4);
  float* pooled = (float*)carve((size_t)kN * kD * 4);
  float* x2 = (float*)carve((size_t)kN * kD * 4);

  k_detect<<<1, 256, 0, stream>>>(ew, flag);
  k_adj<<<kV, 256, 0, stream>>>(ew, flag, cnt_s, cnt_o, Amat);

  float* outp = (float*)d_out;
  for (int u = 0; u < 2; ++u) {
    const float* x = (u == 0) ? obj : x2;
    k_stats1<<<256, 256, 0, stream>>>(x, cnt_s, cnt_o, p1);
    k_fin1<<<1, 256, 0, stream>>>(p1, prm[u][0], prm[u][1], coef1);
    k_gemm<<<kN / 128, 256, 0, stream>>>(x, prm[u][2], 2 * kD, 0,
                                         coef1, coef1 + 128, ys, nullptr, nullptr);
    k_gemm<<<kN / 128, 256, 0, stream>>>(x, prm[u][2], 2 * kD, kD,
                                         coef1 + 256, coef1 + 384, yo, nullptr, nullptr);
    k_poolg<<<kV, 256, 0, stream>>>(ys, yo, Amat, prm[u][3], pooled, p2);
    k_fin2<<<1, 128, 0, stream>>>(p2, prm[u][4], prm[u][5], coef2);
    k_gemm<<<kN / 128, 256, 0, stream>>>(pooled, prm[u][6], kD, 0,
                                         coef2, coef2 + 128,
                                         (u == 0) ? x2 : outp, prm[u][7],
                                         (u == 0) ? nullptr : obj);
  }
}

// Round 3
// 262.352 us; speedup vs baseline: 1.3810x; 1.1315x over previous
//
#include <hip/hip_runtime.h>

namespace {
constexpr int kV = 256, kO = 128, kE = 1024, kD = 128;
constexpr int kN = kV * kO;    // 32768 nodes
constexpr int kVE = kV * kE;   // 262144 edges
constexpr float kEps = 1e-5f;
}

typedef __attribute__((ext_vector_type(8))) short bf16x8;
typedef __attribute__((ext_vector_type(4))) float f32x4;

__device__ __forceinline__ unsigned short f2bf(float x) {
  unsigned u = __float_as_uint(x);
  return (unsigned short)((u + 0x7FFFu + ((u >> 16) & 1u)) >> 16);
}

// ---- K0: detect whether edges buffer is int64 (hi words all zero) or int32 ----
__global__ void k_detect(const unsigned int* __restrict__ ew, int* __restrict__ flag) {
  __shared__ int any;
  if (threadIdx.x == 0) any = 0;
  __syncthreads();
  int local = 0;
  for (int i = threadIdx.x; i < 8192; i += blockDim.x)
    if (ew[2 * i + 1] != 0u) local = 1;
  if (local) atomicOr(&any, 1);
  __syncthreads();
  if (threadIdx.x == 0) *flag = (any == 0) ? 1 : 0;  // 1 => int64 layout
}

// ---- K1: per-graph count matrix A[s][o] + row/col sums (src/dst degree) ----
__global__ __launch_bounds__(256) void k_adj(
    const unsigned int* __restrict__ ew, const int* __restrict__ flag,
    int* __restrict__ cnt_s, int* __restrict__ cnt_o,
    unsigned short* __restrict__ A) {
  __shared__ int cnt[kO * kO];  // 64 KiB
  int v = blockIdx.x, t = threadIdx.x;
  for (int i = t; i < kO * kO; i += 256) cnt[i] = 0;
  __syncthreads();
  bool is64 = (*flag != 0);
  for (int e = t; e < kE; e += 256) {
    long long base = (long long)(v * kE + e) * 3;
    unsigned int s, o;
    if (is64) { s = ew[2 * (base + 0)]; o = ew[2 * (base + 2)]; }
    else      { s = ew[base + 0];       o = ew[base + 2]; }
    s &= 127u; o &= 127u;
    atomicAdd(&cnt[s * kO + o], 1);
  }
  __syncthreads();
  unsigned int* A32 = (unsigned int*)(A + (size_t)v * kO * kO);
  for (int i = t; i < kO * kO / 2; i += 256) {
    unsigned int lo = (unsigned int)cnt[2 * i], hi = (unsigned int)cnt[2 * i + 1];
    A32[i] = lo | (hi << 16);
  }
  if (t < kO) {
    int s = 0;
    for (int c = 0; c < kO; ++c) s += cnt[t * kO + ((c + t) & 127)];
    cnt_s[v * kO + t] = s;
  } else {
    int tc = t - kO;
    int s = 0;
    for (int r = 0; r < kO; ++r) s += cnt[((r + tc) & 127) * kO + tc];
    cnt_o[v * kO + tc] = s;
  }
}

// ---- K1b: split weight matrices into bf16 hi/lo (exact residual split) ----
__global__ __launch_bounds__(256) void k_wsplit(
    const float* __restrict__ s0, const float* __restrict__ s1,
    const float* __restrict__ s2, const float* __restrict__ s3,
    unsigned short* __restrict__ h0, unsigned short* __restrict__ l0,
    unsigned short* __restrict__ h1, unsigned short* __restrict__ l1,
    unsigned short* __restrict__ h2, unsigned short* __restrict__ l2,
    unsigned short* __restrict__ h3, unsigned short* __restrict__ l3) {
  const float* s[4] = {s0, s1, s2, s3};
  unsigned short* hh[4] = {h0, h1, h2, h3};
  unsigned short* ll[4] = {l0, l1, l2, l3};
  const int ns[4] = {kD * 2 * kD, kD * kD, kD * 2 * kD, kD * kD};
  int i0 = blockIdx.x * 256 + threadIdx.x, stride = gridDim.x * 256;
#pragma unroll
  for (int a = 0; a < 4; ++a) {
    for (int i = i0; i < ns[a]; i += stride) {
      float x = s[a][i];
      unsigned short hb = f2bf(x);
      hh[a][i] = hb;
      ll[a][i] = f2bf(x - __uint_as_float((unsigned)hb << 16));
    }
  }
}

// ---- K2: count-weighted per-column sums / sumsq of x (BN1 stats partials) ----
__global__ __launch_bounds__(256) void k_stats1(
    const float* __restrict__ x, const int* __restrict__ cnt_s,
    const int* __restrict__ cnt_o, float* __restrict__ p1) {
  __shared__ float red[8][128];
  int b = blockIdx.x, t = threadIdx.x;
  int dq = (t & 31) * 4, rg = t >> 5;
  float acc[4][4];
#pragma unroll
  for (int a = 0; a < 4; ++a)
#pragma unroll
    for (int j = 0; j < 4; ++j) acc[a][j] = 0.f;
  for (int k = 0; k < 16; ++k) {
    int n = b * 128 + rg + k * 8;
    float4 xv = *(const float4*)(x + (size_t)n * kD + dq);
    float wsv = (float)cnt_s[n], wov = (float)cnt_o[n];
    float xs[4] = {xv.x, xv.y, xv.z, xv.w};
#pragma unroll
    for (int j = 0; j < 4; ++j) {
      acc[0][j] += wsv * xs[j];
      acc[1][j] += wsv * xs[j] * xs[j];
      acc[2][j] += wov * xs[j];
      acc[3][j] += wov * xs[j] * xs[j];
    }
  }
  for (int st = 0; st < 4; ++st) {
    __syncthreads();
#pragma unroll
    for (int j = 0; j < 4; ++j) red[rg][dq + j] = acc[st][j];
    __syncthreads();
    if (t < 128) {
      float s = 0.f;
#pragma unroll
      for (int g = 0; g < 8; ++g) s += red[g][t];
      p1[((size_t)b * 4 + st) * 128 + t] = s;
    }
  }
}

// ---- K3: finalize BN1 -> affine coeffs a,beta for src half and dst half ----
__global__ void k_fin1(const float* __restrict__ p1, const float* __restrict__ g1,
                       const float* __restrict__ b1, float* __restrict__ coef) {
  int c = threadIdx.x;
  if (c >= 256) return;
  int half = c >> 7, d = c & 127;
  double S = 0.0, Q = 0.0;
  for (int b = 0; b < 256; ++b) {
    S += p1[((size_t)b * 4 + half * 2 + 0) * 128 + d];
    Q += p1[((size_t)b * 4 + half * 2 + 1) * 128 + d];
  }
  double m = S / (double)kVE;
  double var = Q / (double)kVE - m * m;
  float a = g1[c] / sqrtf((float)var + kEps);
  float beta = b1[c] - (float)m * a;
  coef[half * 256 + d] = a;
  coef[half * 256 + 128 + d] = beta;
}

// ---- GEMM via MFMA bf16x3: Y[n][j] = sum_d relu(a*X+b)[n][d] * W[j][colOff+d] ----
// A-tile: BN+ReLU transform of X rows, split to bf16 hi/lo in LDS (XOR-swizzled).
// B: pre-split Whi/Wlo read from global (L2-resident). 4 waves, 32 rows/wave.
__global__ __launch_bounds__(256, 1) void k_gemm(
    const float* __restrict__ X,
    const unsigned short* __restrict__ Whi, const unsigned short* __restrict__ Wlo,
    int wStride, int wColOff,
    const float* __restrict__ coefA, const float* __restrict__ coefB,
    float* __restrict__ Y, const float* __restrict__ bias, const float* __restrict__ resid) {
  __shared__ __align__(16) unsigned short Ah[128 * 128];
  __shared__ __align__(16) unsigned short Al[128 * 128];
  int t = threadIdx.x, rb = blockIdx.x;
  int dq = (t & 31) * 4, rg = t >> 5;
  float4 av = *(const float4*)(coefA + dq);
  float4 bv = *(const float4*)(coefB + dq);
  for (int k = 0; k < 16; ++k) {
    int r = rg + k * 8;
    float4 xv = *(const float4*)(X + ((size_t)rb * 128 + r) * kD + dq);
    float h[4] = {fmaxf(av.x * xv.x + bv.x, 0.f), fmaxf(av.y * xv.y + bv.y, 0.f),
                  fmaxf(av.z * xv.z + bv.z, 0.f), fmaxf(av.w * xv.w + bv.w, 0.f)};
    unsigned short hi[4], lo[4];
#pragma unroll
    for (int j = 0; j < 4; ++j) {
      hi[j] = f2bf(h[j]);
      lo[j] = f2bf(h[j] - __uint_as_float((unsigned)hi[j] << 16));
    }
    int idx = r * 128 + (dq ^ ((r & 7) << 3));
    *(ushort4*)(Ah + idx) = make_ushort4(hi[0], hi[1], hi[2], hi[3]);
    *(ushort4*)(Al + idx) = make_ushort4(lo[0], lo[1], lo[2], lo[3]);
  }
  __syncthreads();
  int lane = t & 63, wid = t >> 6;
  int wr0 = wid * 32;
  int lrow = lane & 15, lkc = lane >> 4;  // fragment row/col index, k-chunk
  f32x4 acc[2][8];
#pragma unroll
  for (int i = 0; i < 2; ++i)
#pragma unroll
    for (int j = 0; j < 8; ++j) acc[i][j] = (f32x4){0.f, 0.f, 0.f, 0.f};
  size_t wlane = (size_t)lrow * wStride + wColOff + lkc * 8;
  for (int ks = 0; ks < 4; ++ks) {
    int k0 = ks * 32;
    bf16x8 bh[8], bl[8];
#pragma unroll
    for (int jg = 0; jg < 8; ++jg) {
      size_t wo = wlane + (size_t)(jg * 16) * wStride + k0;
      bh[jg] = *(const bf16x8*)(Whi + wo);
      bl[jg] = *(const bf16x8*)(Wlo + wo);
    }
    bf16x8 ah[2], al[2];
#pragma unroll
    for (int ri = 0; ri < 2; ++ri) {
      int arow = wr0 + ri * 16 + lrow;
      int aidx = arow * 128 + ((k0 + lkc * 8) ^ ((arow & 7) << 3));
      ah[ri] = *(const bf16x8*)(Ah + aidx);
      al[ri] = *(const bf16x8*)(Al + aidx);
    }
#pragma unroll
    for (int ri = 0; ri < 2; ++ri)
#pragma unroll
      for (int jg = 0; jg < 8; ++jg) {
        acc[ri][jg] = __builtin_amdgcn_mfma_f32_16x16x32_bf16(ah[ri], bh[jg], acc[ri][jg], 0, 0, 0);
        acc[ri][jg] = __builtin_amdgcn_mfma_f32_16x16x32_bf16(ah[ri], bl[jg], acc[ri][jg], 0, 0, 0);
        acc[ri][jg] = __builtin_amdgcn_mfma_f32_16x16x32_bf16(al[ri], bh[jg], acc[ri][jg], 0, 0, 0);
      }
  }
  // epilogue: C/D layout col=lane&15, row=(lane>>4)*4+reg (verified m89)
#pragma unroll
  for (int ri = 0; ri < 2; ++ri) {
#pragma unroll
    for (int jg = 0; jg < 8; ++jg) {
      int col = jg * 16 + lrow;
      float bcol = bias ? bias[col] : 0.f;
#pragma unroll
      for (int q = 0; q < 4; ++q) {
        int row = wr0 + ri * 16 + lkc * 4 + q;
        size_t n = (size_t)rb * 128 + row;
        float v = acc[ri][jg][q] + bcol;
        if (resid) v += resid[n * kD + col];
        Y[n * kD + col] = v;
      }
    }
  }
}

// ---- K5: per-graph pooled = ys + lb1 + (A @ yo) / cnt ; fused BN2 partials ----
__global__ __launch_bounds__(256, 1) void k_poolg(
    const float* __restrict__ ys, const float* __restrict__ yo,
    const unsigned short* __restrict__ A, const float* __restrict__ lb1,
    float* __restrict__ pooled, float* __restrict__ p2) {
  __shared__ __align__(16) float Af[kO * kO];   // [s][k] swizzled
  __shared__ __align__(16) float yol[kO * kD];  // [k][d] linear
  int v = blockIdx.x, t = threadIdx.x;
  int dq = (t & 31) * 4, rg = t >> 5;
  const unsigned int* A32 = (const unsigned int*)(A + (size_t)v * kO * kO);
  for (int k = 0; k < 32; ++k) {
    int idx = t + k * 256;
    unsigned int a2 = A32[idx];
    int base = idx * 2;
    int row = base >> 7, col = base & 127;
    int sw = col ^ (((row >> 3) & 7) << 2);
    *(float2*)(Af + row * kO + sw) = make_float2((float)(a2 & 0xFFFFu), (float)(a2 >> 16));
  }
  for (int k = 0; k < 16; ++k) {
    int r = rg + k * 8;
    *(float4*)(yol + r * kD + dq) =
        *(const float4*)(yo + ((size_t)(v * kO + r)) * kD + dq);
  }
  __syncthreads();
  int tc = t & 15, tr = t >> 4;
  int r0 = tr * 8, j0 = tc * 8;
  int asw = (tr & 7) << 2;
  float acc[8][8], rs[8];
#pragma unroll
  for (int i = 0; i < 8; ++i) {
    rs[i] = 0.f;
#pragma unroll
    for (int k = 0; k < 8; ++k) acc[i][k] = 0.f;
  }
  for (int k0 = 0; k0 < 128; k0 += 4) {
    int ad = k0 ^ asw;
    float4 av[8];
#pragma unroll
    for (int i = 0; i < 8; ++i) av[i] = *(const float4*)(Af + (r0 + i) * kO + ad);
    float4 b0[4], b1[4];
#pragma unroll
    for (int kk = 0; kk < 4; ++kk) {
      b0[kk] = *(const float4*)(yol + (k0 + kk) * kD + j0);
      b1[kk] = *(const float4*)(yol + (k0 + kk) * kD + j0 + 4);
    }
#pragma unroll
    for (int i = 0; i < 8; ++i) {
      rs[i] += av[i].x + av[i].y + av[i].z + av[i].w;
      acc[i][0] += av[i].x * b0[0].x + av[i].y * b0[1].x + av[i].z * b0[2].x + av[i].w * b0[3].x;
      acc[i][1] += av[i].x * b0[0].y + av[i].y * b0[1].y + av[i].z * b0[2].y + av[i].w * b0[3].y;
      acc[i][2] += av[i].x * b0[0].z + av[i].y * b0[1].z + av[i].z * b0[2].z + av[i].w * b0[3].z;
      acc[i][3] += av[i].x * b0[0].w + av[i].y * b0[1].w + av[i].z * b0[2].w + av[i].w * b0[3].w;
      acc[i][4] += av[i].x * b1[0].x + av[i].y * b1[1].x + av[i].z * b1[2].x + av[i].w * b1[3].x;
      acc[i][5] += av[i].x * b1[0].y + av[i].y * b1[1].y + av[i].z * b1[2].y + av[i].w * b1[3].y;
      acc[i][6] += av[i].x * b1[0].z + av[i].y * b1[1].z + av[i].z * b1[2].z + av[i].w * b1[3].z;
      acc[i][7] += av[i].x * b1[0].w + av[i].y * b1[1].w + av[i].z * b1[2].w + av[i].w * b1[3].w;
    }
  }
  __syncthreads();  // reuse Af as reduction scratch
  float4 lv1 = *(const float4*)(lb1 + j0);
  float4 lv2 = *(const float4*)(lb1 + j0 + 4);
  float lb[8] = {lv1.x, lv1.y, lv1.z, lv1.w, lv2.x, lv2.y, lv2.z, lv2.w};
  float sm[8], sq[8];
#pragma unroll
  for (int k = 0; k < 8; ++k) { sm[k] = 0.f; sq[k] = 0.f; }
#pragma unroll
  for (int i = 0; i < 8; ++i) {
    size_t n = (size_t)v * kO + r0 + i;
    float pv[8];
    if (rs[i] > 0.f) {
      float inv = 1.f / rs[i];
      float4 y1 = *(const float4*)(ys + n * kD + j0);
      float4 y2 = *(const float4*)(ys + n * kD + j0 + 4);
      float yv[8] = {y1.x, y1.y, y1.z, y1.w, y2.x, y2.y, y2.z, y2.w};
#pragma unroll
      for (int k = 0; k < 8; ++k) pv[k] = yv[k] + lb[k] + acc[i][k] * inv;
    } else {
#pragma unroll
      for (int k = 0; k < 8; ++k) pv[k] = 0.f;
    }
    *(float4*)(pooled + n * kD + j0)     = make_float4(pv[0], pv[1], pv[2], pv[3]);
    *(float4*)(pooled + n * kD + j0 + 4) = make_float4(pv[4], pv[5], pv[6], pv[7]);
#pragma unroll
    for (int k = 0; k < 8; ++k) { sm[k] += pv[k]; sq[k] += pv[k] * pv[k]; }
  }
  float* red = Af;  // [16][128]
  *(float4*)(red + tr * 128 + j0)     = make_float4(sm[0], sm[1], sm[2], sm[3]);
  *(float4*)(red + tr * 128 + j0 + 4) = make_float4(sm[4], sm[5], sm[6], sm[7]);
  __syncthreads();
  if (t < 128) {
    float s = 0.f;
#pragma unroll
    for (int g = 0; g < 16; ++g) s += red[g * 128 + t];
    p2[((size_t)v * 2 + 0) * 128 + t] = s;
  }
  __syncthreads();
  *(float4*)(red + tr * 128 + j0)     = make_float4(sq[0], sq[1], sq[2], sq[3]);
  *(float4*)(red + tr * 128 + j0 + 4) = make_float4(sq[4], sq[5], sq[6], sq[7]);
  __syncthreads();
  if (t < 128) {
    float s = 0.f;
#pragma unroll
    for (int g = 0; g < 16; ++g) s += red[g * 128 + t];
    p2[((size_t)v * 2 + 1) * 128 + t] = s;
  }
}

// ---- K6: finalize BN2 coeffs ----
__global__ void k_fin2(const float* __restrict__ p2, const float* __restrict__ g2,
                       const float* __restrict__ b2, float* __restrict__ coef2) {
  int d = threadIdx.x;
  if (d >= 128) return;
  double S = 0.0, Q = 0.0;
  for (int v = 0; v < kV; ++v) {
    S += p2[((size_t)v * 2 + 0) * 128 + d];
    Q += p2[((size_t)v * 2 + 1) * 128 + d];
  }
  double m = S / (double)kN, var = Q / (double)kN - m * m;
  float a = g2[d] / sqrtf((float)var + kEps);
  float beta = b2[d] - (float)m * a;
  coef2[d] = a; coef2[128 + d] = beta;
}

extern "C" void kernel_launch(void* const* d_in, const int* in_sizes, int n_in,
                              void* d_out, int out_size, void* d_ws, size_t ws_size,
                              hipStream_t stream) {
  (void)in_sizes; (void)n_in; (void)out_size; (void)ws_size;
  const float* obj = (const float*)d_in[0];
  const unsigned int* ew = (const unsigned int*)d_in[1];
  const float* prm[2][8];
  for (int u = 0; u < 2; ++u)
    for (int p = 0; p < 8; ++p) prm[u][p] = (const float*)d_in[2 + u * 8 + p];
  // prm[u]: 0=g1 1=b1 2=W1 3=lb1 4=g2 5=b2 6=W2 7=lb2

  char* ws = (char*)d_ws;
  size_t off = 0;
  auto carve = [&](size_t bytes) -> char* {
    char* p = ws + off;
    off = (off + bytes + 255) & ~(size_t)255;
    return p;
  };
  int* flag = (int*)carve(4);
  int* cnt_s = (int*)carve((size_t)kN * 4);
  int* cnt_o = (int*)carve((size_t)kN * 4);
  unsigned short* Amat = (unsigned short*)carve((size_t)kV * kO * kO * 2);
  float* p1 = (float*)carve((size_t)256 * 4 * 128 * 4);
  float* p2 = (float*)carve((size_t)kV * 2 * 128 * 4);
  float* coef1 = (float*)carve(512 * 4);
  float* coef2 = (float*)carve(256 * 4);
  unsigned short* w1hi[2], *w1lo[2], *w2hi[2], *w2lo[2];
  for (int u = 0; u < 2; ++u) {
    w1hi[u] = (unsigned short*)carve((size_t)kD * 2 * kD * 2);
    w1lo[u] = (unsigned short*)carve((size_t)kD * 2 * kD * 2);
    w2hi[u] = (unsigned short*)carve((size_t)kD * kD * 2);
    w2lo[u] = (unsigned short*)carve((size_t)kD * kD * 2);
  }
  float* ys = (float*)carve((size_t)kN * kD * 4);
  float* yo = (float*)carve((size_t)kN * kD * 4);
  float* pooled = (float*)carve((size_t)kN * kD * 4);
  float* x2 = (float*)carve((size_t)kN * kD * 4);

  k_detect<<<1, 256, 0, stream>>>(ew, flag);
  k_adj<<<kV, 256, 0, stream>>>(ew, flag, cnt_s, cnt_o, Amat);
  k_wsplit<<<128, 256, 0, stream>>>(prm[0][2], prm[0][6], prm[1][2], prm[1][6],
                                    w1hi[0], w1lo[0], w2hi[0], w2lo[0],
                                    w1hi[1], w1lo[1], w2hi[1], w2lo[1]);

  float* outp = (float*)d_out;
  for (int u = 0; u < 2; ++u) {
    const float* x = (u == 0) ? obj : x2;
    k_stats1<<<256, 256, 0, stream>>>(x, cnt_s, cnt_o, p1);
    k_fin1<<<1, 256, 0, stream>>>(p1, prm[u][0], prm[u][1], coef1);
    k_gemm<<<kN / 128, 256, 0, stream>>>(x, w1hi[u], w1lo[u], 2 * kD, 0,
                                         coef1, coef1 + 128, ys, nullptr, nullptr);
    k_gemm<<<kN / 128, 256, 0, stream>>>(x, w1hi[u], w1lo[u], 2 * kD, kD,
                                         coef1 + 256, coef1 + 384, yo, nullptr, nullptr);
    k_poolg<<<kV, 256, 0, stream>>>(ys, yo, Amat, prm[u][3], pooled, p2);
    k_fin2<<<1, 128, 0, stream>>>(p2, prm[u][4], prm[u][5], coef2);
    k_gemm<<<kN / 128, 256, 0, stream>>>(pooled, w2hi[u], w2lo[u], kD, 0,
                                         coef2, coef2 + 128,
                                         (u == 0) ? x2 : outp, prm[u][7],
                                         (u == 0) ? nullptr : obj);
  }
}